// Round 1
// baseline (708.304 us; speedup 1.0000x reference)
//
#include <hip/hip_runtime.h>
#include <hip/hip_bf16.h>

// Problem constants (B=2, S=1024, D=1024, F=4096, E=8)
#define T_TOK 2048
#define DD 1024
#define FF 4096
#define EE 8

typedef __attribute__((ext_vector_type(8))) short short8;
typedef __attribute__((ext_vector_type(4))) float floatx4;

// fp32 -> bf16 round-to-nearest-even, returned as raw u16
static __device__ __forceinline__ unsigned short f2bf_u(float f){
  unsigned u = __float_as_uint(f);
  unsigned r = u + 0x7fffu + ((u >> 16) & 1u);
  return (unsigned short)(r >> 16);
}

// ---------------------------------------------------------------------------
// Router layer 1: H = relu(X @ W1 + b1), fp32 (argmax precision cliff forbids
// bf16 here). M=2048 N=1024 K=1024. BM=BN=64, BK=16, 256 thr, 4x4 microtile.
// Also zeroes the expert counters (runs before router_logits_argmax in-stream).
// ---------------------------------------------------------------------------
__global__ __launch_bounds__(256) void router_gemm1(
    const float* __restrict__ X, const float* __restrict__ W,
    const float* __restrict__ bias, float* __restrict__ H, int* counts)
{
  if (blockIdx.x == 0 && blockIdx.y == 0 && threadIdx.x < EE) counts[threadIdx.x] = 0;
  __shared__ float As[16][68];   // [k][m], +4 pad breaks bank aliasing
  __shared__ float Bs[16][68];   // [k][n]
  const int tid = threadIdx.x;
  const int tx = tid & 15, ty = tid >> 4;
  const int bm = blockIdx.y * 64, bn = blockIdx.x * 64;
  const int ar = tid >> 2, ak = (tid & 3) * 4;   // A stage: 4 thr/row
  const int bk = tid >> 4, bn0 = (tid & 15) * 4; // B stage: 16 thr/row
  float acc[4][4] = {};
  for (int kt = 0; kt < DD; kt += 16){
    float4 a = *(const float4*)(X + (size_t)(bm + ar) * DD + kt + ak);
    float4 b = *(const float4*)(W + (size_t)(kt + bk) * DD + bn + bn0);
    __syncthreads();
    As[ak+0][ar] = a.x; As[ak+1][ar] = a.y; As[ak+2][ar] = a.z; As[ak+3][ar] = a.w;
    *(float4*)&Bs[bk][bn0] = b;
    __syncthreads();
    #pragma unroll
    for (int k = 0; k < 16; ++k){
      float4 av = *(const float4*)&As[k][ty*4];
      float4 bv = *(const float4*)&Bs[k][tx*4];
      float am[4] = {av.x, av.y, av.z, av.w};
      float bm4[4] = {bv.x, bv.y, bv.z, bv.w};
      #pragma unroll
      for (int i = 0; i < 4; ++i)
        #pragma unroll
        for (int j = 0; j < 4; ++j)
          acc[i][j] += am[i] * bm4[j];
    }
  }
  #pragma unroll
  for (int i = 0; i < 4; ++i){
    float4 v;
    v.x = fmaxf(acc[i][0] + bias[bn + tx*4 + 0], 0.f);
    v.y = fmaxf(acc[i][1] + bias[bn + tx*4 + 1], 0.f);
    v.z = fmaxf(acc[i][2] + bias[bn + tx*4 + 2], 0.f);
    v.w = fmaxf(acc[i][3] + bias[bn + tx*4 + 3], 0.f);
    *(float4*)(H + (size_t)(bm + ty*4 + i) * DD + bn + tx*4) = v;
  }
}

// ---------------------------------------------------------------------------
// Router layer 2 + argmax (softmax is monotone -> skip it). One wave/token.
// Tie-break: strict '>' scanning ascending e == jnp.argmax first-max.
// ---------------------------------------------------------------------------
__global__ __launch_bounds__(64) void router_logits_argmax(
    const float* __restrict__ H, const float* __restrict__ W2,
    const float* __restrict__ b2, int* __restrict__ eidx, int* __restrict__ counts)
{
  const int t = blockIdx.x;
  const int lane = threadIdx.x;
  const float* h = H + (size_t)t * DD;
  float acc[8] = {0,0,0,0,0,0,0,0};
  for (int d = lane; d < DD; d += 64){
    float hv = h[d];
    float4 w0 = *(const float4*)(W2 + (size_t)d * 8);
    float4 w1 = *(const float4*)(W2 + (size_t)d * 8 + 4);
    acc[0] += hv * w0.x; acc[1] += hv * w0.y; acc[2] += hv * w0.z; acc[3] += hv * w0.w;
    acc[4] += hv * w1.x; acc[5] += hv * w1.y; acc[6] += hv * w1.z; acc[7] += hv * w1.w;
  }
  #pragma unroll
  for (int s = 32; s > 0; s >>= 1)
    #pragma unroll
    for (int e2 = 0; e2 < 8; ++e2)
      acc[e2] += __shfl_down(acc[e2], s, 64);
  if (lane == 0){
    int best = 0; float bv = acc[0] + b2[0];
    #pragma unroll
    for (int e2 = 1; e2 < 8; ++e2){
      float v = acc[e2] + b2[e2];
      if (v > bv){ bv = v; best = e2; }
    }
    eidx[t] = best;
    atomicAdd(&counts[best], 1);
  }
}

__global__ void scan_offsets(const int* __restrict__ counts, int* __restrict__ offsets,
                             int* __restrict__ cursors)
{
  if (threadIdx.x == 0 && blockIdx.x == 0){
    int s = 0;
    for (int e = 0; e < EE; ++e){ offsets[e] = s; cursors[e] = s; s += counts[e]; }
    offsets[EE] = s;
  }
}

__global__ __launch_bounds__(256) void scatter_tokens(
    const int* __restrict__ eidx, int* __restrict__ cursors, int* __restrict__ perm)
{
  int t = blockIdx.x * 256 + threadIdx.x;
  if (t < T_TOK){
    int e = eidx[t];
    int p = atomicAdd(&cursors[e], 1);
    perm[p] = t;
  }
}

// ---------------------------------------------------------------------------
// Expert FFN GEMMs, bf16 MFMA 16x16x32.
// FIRST : hid[off+m][:] = relu(X[perm[off+m]][:] @ w1[e] + b1[e])  K=1024 N=4096
// !FIRST: out[perm[off+m]][:] = hid[off+m][:] @ w2[e] + b2[e]      K=4096 N=1024
// Tile 128x64, BK=32. 4 waves; wave w covers rows w*32..w*32+31 (2x4 MFMA tiles).
// LDS: both operands stored [row][k] bf16 with row stride 40 (pad 8) so
// fragments are single 16B ds_read_b128 (A: m=lane&15, k=quad*8+j; B mirrored).
// Weights (fp32 [K][N] global) are transposed+converted to bf16 during staging.
// ---------------------------------------------------------------------------
template<bool FIRST>
__global__ __launch_bounds__(256) void expert_gemm(
    const float* __restrict__ X,
    const unsigned short* __restrict__ hidIn,
    const float* __restrict__ Wall,
    const float* __restrict__ Ball,
    unsigned short* __restrict__ hidOut,
    float* __restrict__ Yout,
    const int* __restrict__ perm,
    const int* __restrict__ offsets)
{
  constexpr int K = FIRST ? DD : FF;
  constexpr int N = FIRST ? FF : DD;
  const int e   = blockIdx.z;
  const int off = offsets[e];
  const int cnt = offsets[e+1] - off;
  const int m0  = blockIdx.y * 128;
  if (m0 >= cnt) return;                  // uniform across block
  const int nb = blockIdx.x * 64;
  const float* W    = Wall + (size_t)e * K * N;
  const float* bias = Ball + (size_t)e * N;

  __shared__ unsigned short As[128 * 40];  // [m][k] stride 40
  __shared__ unsigned short Bs[64 * 40];   // [n][k] stride 40

  const int tid = threadIdx.x;
  // A staging: 2 threads/row, 16 k each
  const int sr = tid >> 1;
  const int sk = (tid & 1) * 16;
  int mrow = m0 + sr; if (mrow > cnt - 1) mrow = cnt - 1;  // clamp (dup row, store-guarded)
  const int grow = off + mrow;
  const float* aF = nullptr;
  const unsigned short* aH = nullptr;
  if constexpr (FIRST) aF = X + (size_t)perm[grow] * DD;
  else                 aH = hidIn + (size_t)grow * FF;

  // B staging: thread handles k-pair (bkk,bkk+1) x 4 n values
  const int bkk = (tid >> 4) * 2;
  const int bnn = tid & 15;

  const int lane = tid & 63;
  const int w    = tid >> 6;
  const int lrow = lane & 15;
  const int lq   = lane >> 4;

  floatx4 acc[2][4];
  #pragma unroll
  for (int i = 0; i < 2; ++i)
    #pragma unroll
    for (int j = 0; j < 4; ++j)
      acc[i][j] = (floatx4){0.f, 0.f, 0.f, 0.f};

  for (int kt = 0; kt < K; kt += 32){
    __syncthreads();
    // ---- stage A tile (128 x 32) ----
    if constexpr (FIRST){
      const float* p = aF + kt + sk;
      float4 f0 = *(const float4*)(p + 0);
      float4 f1 = *(const float4*)(p + 4);
      float4 f2 = *(const float4*)(p + 8);
      float4 f3 = *(const float4*)(p + 12);
      unsigned short* d = As + sr*40 + sk;
      uint4 u0, u1;
      u0.x = f2bf_u(f0.x) | ((unsigned)f2bf_u(f0.y) << 16);
      u0.y = f2bf_u(f0.z) | ((unsigned)f2bf_u(f0.w) << 16);
      u0.z = f2bf_u(f1.x) | ((unsigned)f2bf_u(f1.y) << 16);
      u0.w = f2bf_u(f1.z) | ((unsigned)f2bf_u(f1.w) << 16);
      u1.x = f2bf_u(f2.x) | ((unsigned)f2bf_u(f2.y) << 16);
      u1.y = f2bf_u(f2.z) | ((unsigned)f2bf_u(f2.w) << 16);
      u1.z = f2bf_u(f3.x) | ((unsigned)f2bf_u(f3.y) << 16);
      u1.w = f2bf_u(f3.z) | ((unsigned)f2bf_u(f3.w) << 16);
      *(uint4*)(d)     = u0;
      *(uint4*)(d + 8) = u1;
    } else {
      const unsigned short* p = aH + kt + sk;
      uint4 v0 = *(const uint4*)(p);
      uint4 v1 = *(const uint4*)(p + 8);
      unsigned short* d = As + sr*40 + sk;
      *(uint4*)(d)     = v0;
      *(uint4*)(d + 8) = v1;
    }
    // ---- stage B tile (32 x 64) transposed -> [n][k] ----
    #pragma unroll
    for (int i = 0; i < 4; ++i){
      int n = bnn + 16*i;
      float w0 = W[(size_t)(kt + bkk)     * N + nb + n];
      float w1 = W[(size_t)(kt + bkk + 1) * N + nb + n];
      unsigned pk = f2bf_u(w0) | ((unsigned)f2bf_u(w1) << 16);
      *(unsigned*)(Bs + n*40 + bkk) = pk;   // byte ofs 80n+2*bkk, 4B aligned
    }
    __syncthreads();
    // ---- compute: 8 MFMA / wave ----
    short8 afr[2], bfr[4];
    const unsigned short* Ab = As + (w*32 + lrow)*40 + lq*8;
    afr[0] = *(const short8*)(Ab);
    afr[1] = *(const short8*)(Ab + 16*40);
    const unsigned short* Bb = Bs + lrow*40 + lq*8;
    #pragma unroll
    for (int j = 0; j < 4; ++j) bfr[j] = *(const short8*)(Bb + j*16*40);
    #pragma unroll
    for (int i = 0; i < 2; ++i)
      #pragma unroll
      for (int j = 0; j < 4; ++j)
        acc[i][j] = __builtin_amdgcn_mfma_f32_16x16x32_bf16(afr[i], bfr[j], acc[i][j], 0, 0, 0);
  }

  // ---- epilogue: C/D layout col=lane&15, row=quad*4+reg ----
  #pragma unroll
  for (int i = 0; i < 2; ++i){
    #pragma unroll
    for (int j = 0; j < 4; ++j){
      const int n = nb + j*16 + lrow;
      const float bv = bias[n];
      #pragma unroll
      for (int r = 0; r < 4; ++r){
        int m = m0 + w*32 + i*16 + lq*4 + r;
        if (m < cnt){
          float v = acc[i][j][r] + bv;
          if constexpr (FIRST){
            v = fmaxf(v, 0.f);
            hidOut[(size_t)(off + m) * FF + n] = f2bf_u(v);
          } else {
            Yout[(size_t)perm[off + m] * DD + n] = v;
          }
        }
      }
    }
  }
}

extern "C" void kernel_launch(void* const* d_in, const int* in_sizes, int n_in,
                              void* d_out, int out_size, void* d_ws, size_t ws_size,
                              hipStream_t stream)
{
  const float* X   = (const float*)d_in[0];
  const float* rw1 = (const float*)d_in[1];
  const float* rb1 = (const float*)d_in[2];
  const float* rw2 = (const float*)d_in[3];
  const float* rb2 = (const float*)d_in[4];
  const float* ew1 = (const float*)d_in[5];
  const float* eb1 = (const float*)d_in[6];
  const float* ew2 = (const float*)d_in[7];
  const float* eb2 = (const float*)d_in[8];
  float* out = (float*)d_out;

  char* w = (char*)d_ws;
  float* H = (float*)w;                       w += (size_t)T_TOK * DD * sizeof(float);   // 8 MB
  unsigned short* hid = (unsigned short*)w;   w += (size_t)T_TOK * FF * sizeof(short);   // 16 MB
  int* eidx    = (int*)w;  w += T_TOK * sizeof(int);
  int* perm    = (int*)w;  w += T_TOK * sizeof(int);
  int* counts  = (int*)w;  w += 16 * sizeof(int);
  int* offsets = (int*)w;  w += 16 * sizeof(int);
  int* cursors = (int*)w;

  router_gemm1<<<dim3(DD/64, T_TOK/64), 256, 0, stream>>>(X, rw1, rb1, H, counts);
  router_logits_argmax<<<dim3(T_TOK), 64, 0, stream>>>(H, rw2, rb2, eidx, counts);
  scan_offsets<<<1, 64, 0, stream>>>(counts, offsets, cursors);
  scatter_tokens<<<dim3(T_TOK/256), 256, 0, stream>>>(eidx, cursors, perm);
  expert_gemm<true ><<<dim3(FF/64, T_TOK/128, EE), 256, 0, stream>>>(X, nullptr, ew1, eb1, hid, nullptr, perm, offsets);
  expert_gemm<false><<<dim3(DD/64, T_TOK/128, EE), 256, 0, stream>>>(nullptr, hid, ew2, eb2, nullptr, out, perm, offsets);
}

// Round 2
// 511.292 us; speedup vs baseline: 1.3853x; 1.3853x over previous
//
#include <hip/hip_runtime.h>
#include <hip/hip_bf16.h>

// Problem constants (B=2, S=1024, D=1024, F=4096, E=8)
#define T_TOK 2048
#define DD 1024
#define FF 4096
#define EE 8

typedef __attribute__((ext_vector_type(8))) short short8;
typedef __attribute__((ext_vector_type(4))) short short4v;
typedef __attribute__((ext_vector_type(4))) float floatx4;

// fp32 -> bf16 round-to-nearest-even, raw u16
static __device__ __forceinline__ unsigned f2bf_u(float f){
  unsigned u = __float_as_uint(f);
  unsigned r = u + 0x7fffu + ((u >> 16) & 1u);
  return r >> 16;
}

static __device__ __forceinline__ short8 ldfrag(const unsigned short* p){
  short4v lo = *(const short4v*)p;        // 8B reads: row stride 136B keeps
  short4v hi = *(const short4v*)(p + 4);  // 8B alignment (16B would break on odd rows)
  return __builtin_shufflevector(lo, hi, 0, 1, 2, 3, 4, 5, 6, 7);
}

// ---------------------------------------------------------------------------
// Router layer 1: H = relu(X @ W1 + b1), fp32 (argmax cliff forbids bf16:
// one flipped token = absmax ~0.5 >> 0.0616 threshold).
// 64x64 tile, BK=16, 4x4 microtile, double-buffered LDS, 1 barrier/iter.
// Also zeroes expert counters.
// ---------------------------------------------------------------------------
__global__ __launch_bounds__(256) void router_gemm1(
    const float* __restrict__ X, const float* __restrict__ W,
    const float* __restrict__ bias, float* __restrict__ H, int* counts)
{
  if (blockIdx.x == 0 && blockIdx.y == 0 && threadIdx.x < EE) counts[threadIdx.x] = 0;
  __shared__ float As[2][16][68];   // [k][m]
  __shared__ float Bs[2][16][68];   // [k][n]
  const int tid = threadIdx.x;
  const int tx = tid & 15, ty = tid >> 4;
  const int bm = blockIdx.y * 64, bn = blockIdx.x * 64;
  const int ar = tid >> 2, ak = (tid & 3) * 4;   // A stage: 4 thr/row
  const int bk = tid >> 4, bn0 = (tid & 15) * 4; // B stage: 16 thr/k-row
  const float* aP = X + (size_t)(bm + ar) * DD;
  float acc[4][4] = {};
  float4 pa, pb;

  // prologue
  pa = *(const float4*)(aP + ak);
  pb = *(const float4*)(W + (size_t)bk * DD + bn + bn0);
  As[0][ak+0][ar] = pa.x; As[0][ak+1][ar] = pa.y;
  As[0][ak+2][ar] = pa.z; As[0][ak+3][ar] = pa.w;
  *(float4*)&Bs[0][bk][bn0] = pb;
  __syncthreads();

  for (int it = 0; it < DD/16; ++it){
    if (it + 1 < DD/16){
      const int kt = (it + 1) * 16;
      pa = *(const float4*)(aP + kt + ak);
      pb = *(const float4*)(W + (size_t)(kt + bk) * DD + bn + bn0);
    }
    const int buf = it & 1;
    #pragma unroll
    for (int k = 0; k < 16; ++k){
      float4 av = *(const float4*)&As[buf][k][ty*4];
      float4 bv = *(const float4*)&Bs[buf][k][tx*4];
      float am[4] = {av.x, av.y, av.z, av.w};
      float bm4[4] = {bv.x, bv.y, bv.z, bv.w};
      #pragma unroll
      for (int i = 0; i < 4; ++i)
        #pragma unroll
        for (int j = 0; j < 4; ++j)
          acc[i][j] += am[i] * bm4[j];
    }
    if (it + 1 < DD/16){
      const int nb2 = (it + 1) & 1;
      As[nb2][ak+0][ar] = pa.x; As[nb2][ak+1][ar] = pa.y;
      As[nb2][ak+2][ar] = pa.z; As[nb2][ak+3][ar] = pa.w;
      *(float4*)&Bs[nb2][bk][bn0] = pb;
      __syncthreads();
    }
  }
  #pragma unroll
  for (int i = 0; i < 4; ++i){
    float4 v;
    v.x = fmaxf(acc[i][0] + bias[bn + tx*4 + 0], 0.f);
    v.y = fmaxf(acc[i][1] + bias[bn + tx*4 + 1], 0.f);
    v.z = fmaxf(acc[i][2] + bias[bn + tx*4 + 2], 0.f);
    v.w = fmaxf(acc[i][3] + bias[bn + tx*4 + 3], 0.f);
    *(float4*)(H + (size_t)(bm + ty*4 + i) * DD + bn + tx*4) = v;
  }
}

// ---------------------------------------------------------------------------
// Router layer 2 + argmax (softmax monotone -> skip). One wave/token.
// ---------------------------------------------------------------------------
__global__ __launch_bounds__(64) void router_logits_argmax(
    const float* __restrict__ H, const float* __restrict__ W2,
    const float* __restrict__ b2, int* __restrict__ eidx, int* __restrict__ counts)
{
  const int t = blockIdx.x;
  const int lane = threadIdx.x;
  const float* h = H + (size_t)t * DD;
  float acc[8] = {0,0,0,0,0,0,0,0};
  for (int d = lane; d < DD; d += 64){
    float hv = h[d];
    float4 w0 = *(const float4*)(W2 + (size_t)d * 8);
    float4 w1 = *(const float4*)(W2 + (size_t)d * 8 + 4);
    acc[0] += hv * w0.x; acc[1] += hv * w0.y; acc[2] += hv * w0.z; acc[3] += hv * w0.w;
    acc[4] += hv * w1.x; acc[5] += hv * w1.y; acc[6] += hv * w1.z; acc[7] += hv * w1.w;
  }
  #pragma unroll
  for (int s = 32; s > 0; s >>= 1)
    #pragma unroll
    for (int e2 = 0; e2 < 8; ++e2)
      acc[e2] += __shfl_down(acc[e2], s, 64);
  if (lane == 0){
    int best = 0; float bv = acc[0] + b2[0];
    #pragma unroll
    for (int e2 = 1; e2 < 8; ++e2){
      float v = acc[e2] + b2[e2];
      if (v > bv){ bv = v; best = e2; }
    }
    eidx[t] = best;
    atomicAdd(&counts[best], 1);
  }
}

__global__ void scan_offsets(const int* __restrict__ counts, int* __restrict__ offsets,
                             int* __restrict__ cursors)
{
  if (threadIdx.x == 0 && blockIdx.x == 0){
    int s = 0;
    for (int e = 0; e < EE; ++e){ offsets[e] = s; cursors[e] = s; s += counts[e]; }
    offsets[EE] = s;
  }
}

__global__ __launch_bounds__(256) void scatter_tokens(
    const int* __restrict__ eidx, int* __restrict__ cursors, int* __restrict__ perm)
{
  int t = blockIdx.x * 256 + threadIdx.x;
  if (t < T_TOK){
    int e = eidx[t];
    int p = atomicAdd(&cursors[e], 1);
    perm[p] = t;
  }
}

// ---------------------------------------------------------------------------
// Expert FFN GEMMs, bf16 MFMA 16x16x32, memory-bound on fp32 weight stream.
// FIRST : hid[off+m][:] = relu(X[perm[off+m]][:] @ w1[e] + b1[e])  K=1024 N=4096
// !FIRST: out[perm[off+m]][:] = hid[off+m][:] @ w2[e] + b2[e]      K=4096 N=1024
// Tile 64x64, BK=64, double-buffered LDS + register prefetch, 1 barrier/iter.
// 4 waves in 2x2 quadrants (each 32x32 -> 2x2 frags, 8 MFMA/iter).
// LDS rows [r][k] bf16, stride 68 shorts (136B): 8B-aligned frag reads,
// bank stride 2 -> conflict-free frag reads, ~4-way on staging stores only.
// Weights converted fp32->bf16 in-register during staging.
// ---------------------------------------------------------------------------
template<bool FIRST>
__global__ __launch_bounds__(256) void expert_gemm(
    const float* __restrict__ X,
    const unsigned short* __restrict__ hidIn,
    const float* __restrict__ Wall,
    const float* __restrict__ Ball,
    unsigned short* __restrict__ hidOut,
    float* __restrict__ Yout,
    const int* __restrict__ perm,
    const int* __restrict__ offsets)
{
  constexpr int K = FIRST ? DD : FF;
  constexpr int N = FIRST ? FF : DD;
  constexpr int NIT = K / 64;
  const int e   = blockIdx.z;
  const int off = offsets[e];
  const int cnt = offsets[e+1] - off;
  const int m0  = blockIdx.y * 64;
  if (m0 >= cnt) return;                  // uniform across block
  const int nb = blockIdx.x * 64;
  const float* W    = Wall + (size_t)e * K * N;
  const float* bias = Ball + (size_t)e * N;

  __shared__ unsigned short As[2][64 * 68];
  __shared__ unsigned short Bs[2][64 * 68];

  const int tid = threadIdx.x;
  // A staging: 4 thr/row, 16 consecutive k each
  const int ar = tid >> 2;
  const int ak = (tid & 3) * 16;
  int mrow = m0 + ar; if (mrow >= cnt) mrow = cnt - 1;  // clamp (dup row, store-guarded)
  const float* aF = nullptr;
  const unsigned short* aH = nullptr;
  if constexpr (FIRST) aF = X + (size_t)perm[off + mrow] * DD;
  else                 aH = hidIn + (size_t)(off + mrow) * FF;
  // B staging: thread -> k-pair (bkp,bkp+1) x 8 n values
  const int bkp = (tid >> 3) * 2;   // 0..62
  const int bn0 = (tid & 7) * 8;

  const int lane = tid & 63;
  const int w    = tid >> 6;
  const int wm   = (w & 1) * 32;
  const int wn   = (w >> 1) * 32;
  const int lrow = lane & 15;
  const int lq   = lane >> 4;

  floatx4 acc[2][2];
  #pragma unroll
  for (int i = 0; i < 2; ++i)
    #pragma unroll
    for (int j = 0; j < 2; ++j)
      acc[i][j] = (floatx4){0.f, 0.f, 0.f, 0.f};

  // prefetch registers
  float4 fa[4]; uint4 ha[2];
  float4 fb[4];

  auto issue = [&](int kt){
    if constexpr (FIRST){
      #pragma unroll
      for (int i = 0; i < 4; ++i) fa[i] = *(const float4*)(aF + kt + ak + i*4);
    } else {
      ha[0] = *(const uint4*)(aH + kt + ak);
      ha[1] = *(const uint4*)(aH + kt + ak + 8);
    }
    const float* r0 = W + (size_t)(kt + bkp) * N + nb + bn0;
    fb[0] = *(const float4*)(r0);
    fb[1] = *(const float4*)(r0 + 4);
    fb[2] = *(const float4*)(r0 + N);
    fb[3] = *(const float4*)(r0 + N + 4);
  };

  auto stage = [&](int buf){
    unsigned short* a = &As[buf][ar*68 + ak];
    if constexpr (FIRST){
      #pragma unroll
      for (int i = 0; i < 4; ++i){
        const float* f = (const float*)&fa[i];
        uint2 p;
        p.x = f2bf_u(f[0]) | (f2bf_u(f[1]) << 16);
        p.y = f2bf_u(f[2]) | (f2bf_u(f[3]) << 16);
        *(uint2*)(a + i*4) = p;
      }
    } else {
      *(uint2*)(a + 0)  = make_uint2(ha[0].x, ha[0].y);
      *(uint2*)(a + 4)  = make_uint2(ha[0].z, ha[0].w);
      *(uint2*)(a + 8)  = make_uint2(ha[1].x, ha[1].y);
      *(uint2*)(a + 12) = make_uint2(ha[1].z, ha[1].w);
    }
    const float* l0 = (const float*)&fb[0];  // row k,   n0..n0+3
    const float* l1 = (const float*)&fb[1];  // row k,   n0+4..n0+7
    const float* h0 = (const float*)&fb[2];  // row k+1, n0..n0+3
    const float* h1 = (const float*)&fb[3];  // row k+1, n0+4..n0+7
    #pragma unroll
    for (int j = 0; j < 4; ++j){
      *(unsigned*)(&Bs[buf][(bn0 + j)*68 + bkp])     = f2bf_u(l0[j]) | (f2bf_u(h0[j]) << 16);
      *(unsigned*)(&Bs[buf][(bn0 + 4 + j)*68 + bkp]) = f2bf_u(l1[j]) | (f2bf_u(h1[j]) << 16);
    }
  };

  auto compute = [&](int buf){
    #pragma unroll
    for (int ks = 0; ks < 2; ++ks){
      short8 afr[2], bfr[2];
      #pragma unroll
      for (int i = 0; i < 2; ++i)
        afr[i] = ldfrag(&As[buf][(wm + i*16 + lrow)*68 + ks*32 + lq*8]);
      #pragma unroll
      for (int j = 0; j < 2; ++j)
        bfr[j] = ldfrag(&Bs[buf][(wn + j*16 + lrow)*68 + ks*32 + lq*8]);
      #pragma unroll
      for (int i = 0; i < 2; ++i)
        #pragma unroll
        for (int j = 0; j < 2; ++j)
          acc[i][j] = __builtin_amdgcn_mfma_f32_16x16x32_bf16(afr[i], bfr[j], acc[i][j], 0, 0, 0);
    }
  };

  // pipeline: issue(k+1) -> compute(k) -> stage(k+1) -> barrier
  issue(0);
  stage(0);
  __syncthreads();
  for (int it = 0; it < NIT; ++it){
    if (it + 1 < NIT) issue((it + 1) * 64);
    compute(it & 1);
    if (it + 1 < NIT){
      stage((it + 1) & 1);
      __syncthreads();
    }
  }

  // epilogue: C/D layout col=lane&15, row=quad*4+reg
  #pragma unroll
  for (int i = 0; i < 2; ++i){
    #pragma unroll
    for (int j = 0; j < 2; ++j){
      const int n = nb + wn + j*16 + lrow;
      const float bv = bias[n];
      #pragma unroll
      for (int r = 0; r < 4; ++r){
        int m = m0 + wm + i*16 + lq*4 + r;
        if (m < cnt){
          float v = acc[i][j][r] + bv;
          if constexpr (FIRST){
            v = fmaxf(v, 0.f);
            hidOut[(size_t)(off + m) * FF + n] = (unsigned short)f2bf_u(v);
          } else {
            Yout[(size_t)perm[off + m] * DD + n] = v;
          }
        }
      }
    }
  }
}

extern "C" void kernel_launch(void* const* d_in, const int* in_sizes, int n_in,
                              void* d_out, int out_size, void* d_ws, size_t ws_size,
                              hipStream_t stream)
{
  const float* X   = (const float*)d_in[0];
  const float* rw1 = (const float*)d_in[1];
  const float* rb1 = (const float*)d_in[2];
  const float* rw2 = (const float*)d_in[3];
  const float* rb2 = (const float*)d_in[4];
  const float* ew1 = (const float*)d_in[5];
  const float* eb1 = (const float*)d_in[6];
  const float* ew2 = (const float*)d_in[7];
  const float* eb2 = (const float*)d_in[8];
  float* out = (float*)d_out;

  char* w = (char*)d_ws;
  float* H = (float*)w;                       w += (size_t)T_TOK * DD * sizeof(float);   // 8 MB
  unsigned short* hid = (unsigned short*)w;   w += (size_t)T_TOK * FF * sizeof(short);   // 16 MB
  int* eidx    = (int*)w;  w += T_TOK * sizeof(int);
  int* perm    = (int*)w;  w += T_TOK * sizeof(int);
  int* counts  = (int*)w;  w += 16 * sizeof(int);
  int* offsets = (int*)w;  w += 16 * sizeof(int);
  int* cursors = (int*)w;

  router_gemm1<<<dim3(DD/64, T_TOK/64), 256, 0, stream>>>(X, rw1, rb1, H, counts);
  router_logits_argmax<<<dim3(T_TOK), 64, 0, stream>>>(H, rw2, rb2, eidx, counts);
  scan_offsets<<<1, 64, 0, stream>>>(counts, offsets, cursors);
  scatter_tokens<<<dim3(T_TOK/256), 256, 0, stream>>>(eidx, cursors, perm);
  expert_gemm<true ><<<dim3(FF/64, T_TOK/64, EE), 256, 0, stream>>>(X, nullptr, ew1, eb1, hid, nullptr, perm, offsets);
  expert_gemm<false><<<dim3(DD/64, T_TOK/64, EE), 256, 0, stream>>>(nullptr, hid, ew2, eb2, nullptr, out, perm, offsets);
}